// Round 1
// baseline (326.611 us; speedup 1.0000x reference)
//
#include <hip/hip_runtime.h>
#include <hip/hip_bf16.h>

// Problem constants
#define IN_DIM 128
#define HID    64
#define NFW    8256     // IN*HID + HID
#define BATCH  256
#define K2     16512    // 2*NFW
#define NKT    258      // K2 / 64  (K-tiles for gemm_M)

typedef float f32x4 __attribute__((ext_vector_type(4)));
typedef short bf16x8 __attribute__((ext_vector_type(8)));

__device__ __forceinline__ unsigned int f2bf(float f) {
    union { float f; unsigned int u; } v; v.f = f;
    return (v.u + 0x7FFFu + ((v.u >> 16) & 1u)) >> 16;   // RNE f32->bf16 (bits)
}

// ---------------------------------------------------------------------------
// Kernel 0: W1 (16512x128 f32, row-major) -> W1T tiled bf16.
// Tile kt (64 k-rows): layout [128 n][64 kl] bf16, contiguous 16KB per tile.
// W1T[kt*8192 + n*64 + kl] = bf16(W1[kt*64+kl][n])
// ---------------------------------------------------------------------------
__global__ __launch_bounds__(256) void k_prep_w1t(const float* __restrict__ W1,
                                                  unsigned short* __restrict__ W1T) {
    __shared__ float tile[64][IN_DIM + 1];   // +1 pad: conflict-free col reads
    const int kt = blockIdx.x;               // 0..257
    const int t  = threadIdx.x;
    const float* src = W1 + (size_t)kt * 64 * IN_DIM;
#pragma unroll
    for (int p = 0; p < 8; ++p) {
        int c4 = p * 256 + t;                 // float4 index (2048 total)
        int e = c4 * 4;
        int row = e >> 7, col = e & 127;
        f32x4 v = *reinterpret_cast<const f32x4*>(src + row * IN_DIM + col);
        tile[row][col+0] = v.x; tile[row][col+1] = v.y;
        tile[row][col+2] = v.z; tile[row][col+3] = v.w;
    }
    __syncthreads();
    unsigned short* dst = W1T + (size_t)kt * (IN_DIM * 64);
#pragma unroll
    for (int it = 0; it < 4; ++it) {
        int c = it * 256 + t;                 // 8-elem chunk (1024 total)
        int n = c >> 3, kl0 = (c & 7) * 8;
        uint4 w;
        w.x = f2bf(tile[kl0+0][n]) | (f2bf(tile[kl0+1][n]) << 16);
        w.y = f2bf(tile[kl0+2][n]) | (f2bf(tile[kl0+3][n]) << 16);
        w.z = f2bf(tile[kl0+4][n]) | (f2bf(tile[kl0+5][n]) << 16);
        w.w = f2bf(tile[kl0+6][n]) | (f2bf(tile[kl0+7][n]) << 16);
        *reinterpret_cast<uint4*>(dst + c * 8) = w;   // coalesced 16B/lane
    }
}

// ---------------------------------------------------------------------------
// Kernel 1 (the big one, HBM-bound): M = W2(8256x16512) * W1(16512x128).
// 258 wgs x 256 thr (4 waves). BM=32, BN=128, BK=64. Reg-staged fp32->bf16
// into padded LDS (stride 72 ushorts = 144B -> conflict-free b128 frag reads).
// Wave (wm,wn) owns 16 rows x 64 cols; 8 MFMA 16x16x32 per K-step.
// Output: M as bf16 rows [j][d] (2.1 MB), consumed by kernel 2.
// ---------------------------------------------------------------------------
__global__ __launch_bounds__(256) void k_gemm_M(const float* __restrict__ W2,
                                                const unsigned short* __restrict__ W1T,
                                                unsigned short* __restrict__ Mout) {
    __shared__ unsigned short Ash[32][72];    // 4.6 KB
    __shared__ unsigned short Bsh[128][72];   // 18.4 KB
    const int t = threadIdx.x;
    const int m0 = blockIdx.x * 32;
    const int lane = t & 63, wid = t >> 6;
    const int wm = wid >> 1, wn = wid & 1;
    const int l15 = lane & 15, l4 = lane >> 4;

    // staging assignment
    const int ar = t >> 3;                    // A row 0..31
    const int ak = (t & 7) * 8;               // A k-offset within tile
    const float* aptr = W2 + (size_t)(m0 + ar) * K2 + ak;
    const int bn = t >> 1;                    // B row (n) 0..127
    const int bk = (t & 1) * 32;              // B k-offset

    // prologue: load tile kt=0 into regs
    f32x4 a0 = *reinterpret_cast<const f32x4*>(aptr);
    f32x4 a1 = *reinterpret_cast<const f32x4*>(aptr + 4);
    uint4 b0 = *reinterpret_cast<const uint4*>(W1T + t * 32);
    uint4 b1 = *reinterpret_cast<const uint4*>(W1T + t * 32 + 8);
    uint4 b2 = *reinterpret_cast<const uint4*>(W1T + t * 32 + 16);
    uint4 b3 = *reinterpret_cast<const uint4*>(W1T + t * 32 + 24);

    f32x4 acc[4];
#pragma unroll
    for (int nf = 0; nf < 4; ++nf) acc[nf] = (f32x4){0.f, 0.f, 0.f, 0.f};

    for (int kt = 0; kt < NKT; ++kt) {
        if (kt > 0) __syncthreads();          // prev compute done reading LDS
        // store staged regs -> LDS (A: cvt fp32->bf16)
        uint4 aw;
        aw.x = f2bf(a0.x) | (f2bf(a0.y) << 16);
        aw.y = f2bf(a0.z) | (f2bf(a0.w) << 16);
        aw.z = f2bf(a1.x) | (f2bf(a1.y) << 16);
        aw.w = f2bf(a1.z) | (f2bf(a1.w) << 16);
        *reinterpret_cast<uint4*>(&Ash[ar][ak]) = aw;
        *reinterpret_cast<uint4*>(&Bsh[bn][bk +  0]) = b0;
        *reinterpret_cast<uint4*>(&Bsh[bn][bk +  8]) = b1;
        *reinterpret_cast<uint4*>(&Bsh[bn][bk + 16]) = b2;
        *reinterpret_cast<uint4*>(&Bsh[bn][bk + 24]) = b3;
        __syncthreads();
        // issue next tile's global loads early (latency hides under MFMA)
        if (kt + 1 < NKT) {
            const float* ap = aptr + (kt + 1) * 64;
            a0 = *reinterpret_cast<const f32x4*>(ap);
            a1 = *reinterpret_cast<const f32x4*>(ap + 4);
            const unsigned short* bp = W1T + (size_t)(kt + 1) * 8192 + t * 32;
            b0 = *reinterpret_cast<const uint4*>(bp);
            b1 = *reinterpret_cast<const uint4*>(bp + 8);
            b2 = *reinterpret_cast<const uint4*>(bp + 16);
            b3 = *reinterpret_cast<const uint4*>(bp + 24);
        }
        // compute current tile from LDS
#pragma unroll
        for (int kk = 0; kk < 2; ++kk) {
            bf16x8 af = *reinterpret_cast<const bf16x8*>(&Ash[wm * 16 + l15][kk * 32 + l4 * 8]);
#pragma unroll
            for (int nf = 0; nf < 4; ++nf) {
                bf16x8 bfr = *reinterpret_cast<const bf16x8*>(&Bsh[wn * 64 + nf * 16 + l15][kk * 32 + l4 * 8]);
                acc[nf] = __builtin_amdgcn_mfma_f32_16x16x32_bf16(af, bfr, acc[nf], 0, 0, 0);
            }
        }
    }
    // epilogue: C/D layout col=lane&15, row=(lane>>4)*4+r  -> M_bf16[j][d]
    const int jrow = m0 + wm * 16 + l4 * 4;
    const int dcol = wn * 64 + l15;
#pragma unroll
    for (int nf = 0; nf < 4; ++nf)
#pragma unroll
        for (int r = 0; r < 4; ++r)
            Mout[(size_t)(jrow + r) * IN_DIM + dcol + nf * 16] =
                (unsigned short)f2bf(acc[nf][r]);
}

// ---------------------------------------------------------------------------
// Kernel 2: U[i][j] = sum_d xs[i][d] * M[j][d].  MFMA, K=128.
// B-frags read k-contiguous directly from M_bf16 rows (L2-hot, 2.1 MB).
// Grid: 4 i-blocks x 129 j-blocks; wave = 16i x 64j.
// ---------------------------------------------------------------------------
__global__ __launch_bounds__(256) void k_gemm_U(const float* __restrict__ xs,
                                                const unsigned short* __restrict__ Mb,
                                                float* __restrict__ U) {
    const int t = threadIdx.x, lane = t & 63, wid = t >> 6;
    const int l15 = lane & 15, l4 = lane >> 4;
    const int bj = blockIdx.x % 129, bi = blockIdx.x / 129;
    const int i0 = bi * 64 + wid * 16;
    const int j0 = bj * 64;
    f32x4 acc[4];
#pragma unroll
    for (int nf = 0; nf < 4; ++nf) acc[nf] = (f32x4){0.f, 0.f, 0.f, 0.f};
#pragma unroll
    for (int kk = 0; kk < 4; ++kk) {
        const float* xp = xs + (size_t)(i0 + l15) * IN_DIM + kk * 32 + l4 * 8;
        f32x4 x0 = *reinterpret_cast<const f32x4*>(xp);
        f32x4 x1 = *reinterpret_cast<const f32x4*>(xp + 4);
        union { bf16x8 v; unsigned short s[8]; } af;
        af.s[0] = f2bf(x0.x); af.s[1] = f2bf(x0.y);
        af.s[2] = f2bf(x0.z); af.s[3] = f2bf(x0.w);
        af.s[4] = f2bf(x1.x); af.s[5] = f2bf(x1.y);
        af.s[6] = f2bf(x1.z); af.s[7] = f2bf(x1.w);
#pragma unroll
        for (int nf = 0; nf < 4; ++nf) {
            const unsigned short* mp = Mb + (size_t)(j0 + nf * 16 + l15) * IN_DIM + kk * 32 + l4 * 8;
            bf16x8 bfr = *reinterpret_cast<const bf16x8*>(mp);
            acc[nf] = __builtin_amdgcn_mfma_f32_16x16x32_bf16(af.v, bfr, acc[nf], 0, 0, 0);
        }
    }
    const int iw = i0 + l4 * 4;
#pragma unroll
    for (int nf = 0; nf < 4; ++nf) {
        const int j = j0 + nf * 16 + l15;
#pragma unroll
        for (int r = 0; r < 4; ++r)
            U[(size_t)(iw + r) * NFW + j] = acc[nf][r];
    }
}

// ---------------------------------------------------------------------------
// Kernel 3: 8256 independent sigmoid chains (sequential in i, parallel in j).
// fw = sigmoid(10*(fw + U[i][j] - 0.5)); FW[i][j] = fw.  Coalesced column walk.
// ---------------------------------------------------------------------------
__global__ __launch_bounds__(256) void k_chains(const float* __restrict__ U,
                                                const float* __restrict__ fw0,
                                                float* __restrict__ FW) {
    const int j = blockIdx.x * 256 + threadIdx.x;
    if (j >= NFW) return;
    float fw = fw0[j];
    const float* up = U + j;
    float* fp = FW + j;
#pragma unroll 4
    for (int i = 0; i < BATCH; ++i) {
        float u = up[(size_t)i * NFW];
        float z = 10.0f * (fw + u - 0.5f);
        fw = 1.0f / (1.0f + __expf(-z));
        fp[(size_t)i * NFW] = fw;
    }
}

// ---------------------------------------------------------------------------
// Kernel 4: preds. Block per i: h = relu(fw1 @ xs_i) (64x128 matvec),
// out[i] = fw2 . h.  Thread t: k=t>>2, quarter q=t&3 sums 32 elems.
// ---------------------------------------------------------------------------
__global__ __launch_bounds__(256) void k_preds(const float* __restrict__ FW,
                                               const float* __restrict__ xs,
                                               float* __restrict__ out) {
    __shared__ float xsh[IN_DIM];
    __shared__ float hsh[HID];
    const int i = blockIdx.x, t = threadIdx.x;
    if (t < 32) {
        f32x4 v = *reinterpret_cast<const f32x4*>(xs + (size_t)i * IN_DIM + t * 4);
        xsh[t*4+0] = v.x; xsh[t*4+1] = v.y; xsh[t*4+2] = v.z; xsh[t*4+3] = v.w;
    }
    __syncthreads();
    const int k = t >> 2, q = t & 3;
    const float* fr = FW + (size_t)i * NFW + k * IN_DIM + q * 32;
    float p = 0.f;
#pragma unroll
    for (int m = 0; m < 8; ++m) {
        f32x4 v = *reinterpret_cast<const f32x4*>(fr + m * 4);
        const int d = q * 32 + m * 4;
        p += v.x * xsh[d] + v.y * xsh[d+1] + v.z * xsh[d+2] + v.w * xsh[d+3];
    }
    p += __shfl_xor(p, 1);
    p += __shfl_xor(p, 2);
    if (q == 0) hsh[k] = fmaxf(p, 0.f);
    __syncthreads();
    if (t < 64) {
        float v = FW[(size_t)i * NFW + IN_DIM * HID + t] * hsh[t];
        v += __shfl_xor(v, 1);  v += __shfl_xor(v, 2);  v += __shfl_xor(v, 4);
        v += __shfl_xor(v, 8);  v += __shfl_xor(v, 16); v += __shfl_xor(v, 32);
        if (t == 0) out[i] = v;
    }
}

// ---------------------------------------------------------------------------
// Workspace layout (needs ~22.2 MiB):
//   W1T bf16 : 4,227,072 B   @ 0
//   M   bf16 : 2,113,536 B   @ 4,227,072
//   U   f32  : 8,454,144 B   @ 6,340,608
//   FW  f32  : 8,454,144 B   @ 14,794,752
// ---------------------------------------------------------------------------
extern "C" void kernel_launch(void* const* d_in, const int* in_sizes, int n_in,
                              void* d_out, int out_size, void* d_ws, size_t ws_size,
                              hipStream_t stream) {
    const float* x   = (const float*)d_in[0];   // (256,1,128)
    const float* W1  = (const float*)d_in[1];   // (16512,128)
    const float* W2  = (const float*)d_in[2];   // (8256,16512)
    const float* fw0 = (const float*)d_in[3];   // (8256,)
    float* out = (float*)d_out;                 // 256 f32

    char* ws = (char*)d_ws;
    unsigned short* W1T = (unsigned short*)(ws);
    unsigned short* Mb  = (unsigned short*)(ws + 4227072);
    float* U  = (float*)(ws + 6340608);
    float* FW = (float*)(ws + 14794752);

    hipLaunchKernelGGL(k_prep_w1t, dim3(258), dim3(256), 0, stream, W1, W1T);
    hipLaunchKernelGGL(k_gemm_M,   dim3(258), dim3(256), 0, stream, W2, W1T, Mb);
    hipLaunchKernelGGL(k_gemm_U,   dim3(516), dim3(256), 0, stream, x, Mb, U);
    hipLaunchKernelGGL(k_chains,   dim3(33),  dim3(256), 0, stream, U, fw0, FW);
    hipLaunchKernelGGL(k_preds,    dim3(256), dim3(256), 0, stream, FW, x, out);
}

// Round 2
// 216.675 us; speedup vs baseline: 1.5074x; 1.5074x over previous
//
#include <hip/hip_runtime.h>
#include <hip/hip_bf16.h>

// Problem constants
#define IN_DIM 128
#define HID    64
#define NFW    8256     // IN*HID + HID
#define BATCH  256
#define K2     16512    // 2*NFW
#define NKT    258      // total K-tiles of 64 for gemm_M
#define BM     192      // rows per m-block (8256 = 192*43)
#define KSPLIT 6        // 258 = 6*43
#define NT_PER 43       // k-tiles per split

typedef float f32x4 __attribute__((ext_vector_type(4)));
typedef short bf16x8 __attribute__((ext_vector_type(8)));

__device__ __forceinline__ unsigned int f2bf(float f) {
    union { float f; unsigned int u; } v; v.f = f;
    return (v.u + 0x7FFFu + ((v.u >> 16) & 1u)) >> 16;   // RNE f32->bf16 (bits)
}

// ---------------------------------------------------------------------------
// Kernel 0: W1 (16512x128 f32, row-major) -> W1T tiled bf16.
// Tile kt (64 k-rows): layout [128 n][64 kl] bf16, contiguous 16KB per tile.
// ---------------------------------------------------------------------------
__global__ __launch_bounds__(256) void k_prep_w1t(const float* __restrict__ W1,
                                                  unsigned short* __restrict__ W1T) {
    __shared__ float tile[64][IN_DIM + 1];
    const int kt = blockIdx.x;               // 0..257
    const int t  = threadIdx.x;
    const float* src = W1 + (size_t)kt * 64 * IN_DIM;
#pragma unroll
    for (int p = 0; p < 8; ++p) {
        int c4 = p * 256 + t;
        int e = c4 * 4;
        int row = e >> 7, col = e & 127;
        f32x4 v = *reinterpret_cast<const f32x4*>(src + row * IN_DIM + col);
        tile[row][col+0] = v.x; tile[row][col+1] = v.y;
        tile[row][col+2] = v.z; tile[row][col+3] = v.w;
    }
    __syncthreads();
    unsigned short* dst = W1T + (size_t)kt * (IN_DIM * 64);
#pragma unroll
    for (int it = 0; it < 4; ++it) {
        int c = it * 256 + t;
        int n = c >> 3, kl0 = (c & 7) * 8;
        uint4 w;
        w.x = f2bf(tile[kl0+0][n]) | (f2bf(tile[kl0+1][n]) << 16);
        w.y = f2bf(tile[kl0+2][n]) | (f2bf(tile[kl0+3][n]) << 16);
        w.z = f2bf(tile[kl0+4][n]) | (f2bf(tile[kl0+5][n]) << 16);
        w.w = f2bf(tile[kl0+6][n]) | (f2bf(tile[kl0+7][n]) << 16);
        *reinterpret_cast<uint4*>(dst + c * 8) = w;
    }
}

// ---------------------------------------------------------------------------
// Kernel 1: split-K GEMM partials. M = W2(8256x16512) * W1(16512x128).
// Grid 258 = 43 m-blocks x 6 k-splits, 512 thr (8 waves, 4m x 2n).
// BM=192, BN=128, BK=64. B traffic cut 1.08GB -> 181MB vs round 1.
// Mpart[ks][j][d] f32.
// ---------------------------------------------------------------------------
__global__ __launch_bounds__(512) void k_gemm_M(const float* __restrict__ W2,
                                                const unsigned short* __restrict__ W1T,
                                                float* __restrict__ Mpart) {
    __shared__ unsigned short Ash[BM][72];    // 27.6 KB (pad: stride 144B)
    __shared__ unsigned short Bsh[128][72];   // 18.4 KB
    const int t = threadIdx.x;
    const int mb = blockIdx.x / KSPLIT, ks = blockIdx.x % KSPLIT;
    const int m0 = mb * BM;
    const int g0 = ks * NT_PER;               // first global k-tile
    const int lane = t & 63, wid = t >> 6;
    const int wm = wid >> 1, wn = wid & 1;    // wave grid 4m x 2n
    const int l15 = lane & 15, l4 = lane >> 4;

    // A staging: 6 passes of 32 rows x 16 lanes (f32x4 each) = 192x64 f32
    const int ar = t >> 4;                    // base row 0..31
    const int ac = (t & 15) * 4;              // float col within 64
    const float* abase = W2 + (size_t)(m0 + ar) * K2 + g0 * 64 + ac;
    // B staging: thread t reads 16 contiguous bf16 of the 8192-elem tile
    const unsigned short* bbase = W1T + (size_t)g0 * 8192 + t * 16;

    f32x4 sa[6];
    uint4 sb0, sb1;
#pragma unroll
    for (int p = 0; p < 6; ++p)
        sa[p] = *reinterpret_cast<const f32x4*>(abase + (size_t)p * 32 * K2);
    sb0 = *reinterpret_cast<const uint4*>(bbase);
    sb1 = *reinterpret_cast<const uint4*>(bbase + 8);

    f32x4 acc[3][4];
#pragma unroll
    for (int mf = 0; mf < 3; ++mf)
#pragma unroll
        for (int nf = 0; nf < 4; ++nf)
            acc[mf][nf] = (f32x4){0.f, 0.f, 0.f, 0.f};

    for (int kt = 0; kt < NT_PER; ++kt) {
        if (kt) __syncthreads();
        // staged regs -> LDS (A: f32 -> bf16)
#pragma unroll
        for (int p = 0; p < 6; ++p) {
            uint2 w;
            w.x = f2bf(sa[p].x) | (f2bf(sa[p].y) << 16);
            w.y = f2bf(sa[p].z) | (f2bf(sa[p].w) << 16);
            *reinterpret_cast<uint2*>(&Ash[p * 32 + ar][ac]) = w;
        }
        *reinterpret_cast<uint4*>(&Bsh[t >> 2][(t & 3) * 16]) = sb0;
        *reinterpret_cast<uint4*>(&Bsh[t >> 2][(t & 3) * 16 + 8]) = sb1;
        __syncthreads();
        // prefetch next tile (latency hides under MFMA + DRAM drain)
        if (kt + 1 < NT_PER) {
            const float* ap = abase + (size_t)(kt + 1) * 64;
#pragma unroll
            for (int p = 0; p < 6; ++p)
                sa[p] = *reinterpret_cast<const f32x4*>(ap + (size_t)p * 32 * K2);
            const unsigned short* bp = bbase + (size_t)(kt + 1) * 8192;
            sb0 = *reinterpret_cast<const uint4*>(bp);
            sb1 = *reinterpret_cast<const uint4*>(bp + 8);
        }
        // compute: 24 MFMA per wave per K-tile
#pragma unroll
        for (int kk = 0; kk < 2; ++kk) {
#pragma unroll
            for (int mf = 0; mf < 3; ++mf) {
                bf16x8 af = *reinterpret_cast<const bf16x8*>(
                    &Ash[wm * 48 + mf * 16 + l15][kk * 32 + l4 * 8]);
#pragma unroll
                for (int nf = 0; nf < 4; ++nf) {
                    bf16x8 bfr = *reinterpret_cast<const bf16x8*>(
                        &Bsh[wn * 64 + nf * 16 + l15][kk * 32 + l4 * 8]);
                    acc[mf][nf] = __builtin_amdgcn_mfma_f32_16x16x32_bf16(af, bfr, acc[mf][nf], 0, 0, 0);
                }
            }
        }
    }
    // epilogue: C/D layout col=lane&15, row=(lane>>4)*4+r
    float* outp = Mpart + (size_t)ks * ((size_t)NFW * IN_DIM);
    const int r0 = m0 + wm * 48;
#pragma unroll
    for (int mf = 0; mf < 3; ++mf)
#pragma unroll
        for (int nf = 0; nf < 4; ++nf)
#pragma unroll
            for (int r = 0; r < 4; ++r)
                outp[(size_t)(r0 + mf * 16 + l4 * 4 + r) * IN_DIM + wn * 64 + nf * 16 + l15] =
                    acc[mf][nf][r];
}

// ---------------------------------------------------------------------------
// Kernel 1b: reduce 6 partials -> M bf16. 1,056,768 f32 = 264,192 f32x4.
// ---------------------------------------------------------------------------
__global__ __launch_bounds__(256) void k_reduce_M(const float* __restrict__ Mpart,
                                                  unsigned short* __restrict__ Mb) {
    const int idx = blockIdx.x * 256 + threadIdx.x;   // f32x4 index
    f32x4 s = (f32x4){0.f, 0.f, 0.f, 0.f};
#pragma unroll
    for (int ks = 0; ks < KSPLIT; ++ks) {
        f32x4 v = *reinterpret_cast<const f32x4*>(
            Mpart + (size_t)ks * ((size_t)NFW * IN_DIM) + (size_t)idx * 4);
        s.x += v.x; s.y += v.y; s.z += v.z; s.w += v.w;
    }
    uint2 o;
    o.x = f2bf(s.x) | (f2bf(s.y) << 16);
    o.y = f2bf(s.z) | (f2bf(s.w) << 16);
    *reinterpret_cast<uint2*>(Mb + (size_t)idx * 4) = o;
}

// ---------------------------------------------------------------------------
// Kernel 2: U[i][j] = sum_d xs[i][d] * M[j][d].  MFMA, K=128.
// ---------------------------------------------------------------------------
__global__ __launch_bounds__(256) void k_gemm_U(const float* __restrict__ xs,
                                                const unsigned short* __restrict__ Mb,
                                                float* __restrict__ U) {
    const int t = threadIdx.x, lane = t & 63, wid = t >> 6;
    const int l15 = lane & 15, l4 = lane >> 4;
    const int bj = blockIdx.x % 129, bi = blockIdx.x / 129;
    const int i0 = bi * 64 + wid * 16;
    const int j0 = bj * 64;
    f32x4 acc[4];
#pragma unroll
    for (int nf = 0; nf < 4; ++nf) acc[nf] = (f32x4){0.f, 0.f, 0.f, 0.f};
#pragma unroll
    for (int kk = 0; kk < 4; ++kk) {
        const float* xp = xs + (size_t)(i0 + l15) * IN_DIM + kk * 32 + l4 * 8;
        f32x4 x0 = *reinterpret_cast<const f32x4*>(xp);
        f32x4 x1 = *reinterpret_cast<const f32x4*>(xp + 4);
        union { bf16x8 v; unsigned short s[8]; } af;
        af.s[0] = f2bf(x0.x); af.s[1] = f2bf(x0.y);
        af.s[2] = f2bf(x0.z); af.s[3] = f2bf(x0.w);
        af.s[4] = f2bf(x1.x); af.s[5] = f2bf(x1.y);
        af.s[6] = f2bf(x1.z); af.s[7] = f2bf(x1.w);
#pragma unroll
        for (int nf = 0; nf < 4; ++nf) {
            const unsigned short* mp = Mb + (size_t)(j0 + nf * 16 + l15) * IN_DIM + kk * 32 + l4 * 8;
            bf16x8 bfr = *reinterpret_cast<const bf16x8*>(mp);
            acc[nf] = __builtin_amdgcn_mfma_f32_16x16x32_bf16(af.v, bfr, acc[nf], 0, 0, 0);
        }
    }
    const int iw = i0 + l4 * 4;
#pragma unroll
    for (int nf = 0; nf < 4; ++nf) {
        const int j = j0 + nf * 16 + l15;
#pragma unroll
        for (int r = 0; r < 4; ++r)
            U[(size_t)(iw + r) * NFW + j] = acc[nf][r];
    }
}

// ---------------------------------------------------------------------------
// Kernel 3: 8256 sigmoid chains; batch-16 load prefetch to hide L3 latency.
// ---------------------------------------------------------------------------
__global__ __launch_bounds__(256) void k_chains(const float* __restrict__ U,
                                                const float* __restrict__ fw0,
                                                float* __restrict__ FW) {
    const int j = blockIdx.x * 256 + threadIdx.x;
    if (j >= NFW) return;
    float fw = fw0[j];
    const float* up = U + j;
    float* fp = FW + j;
    for (int ib = 0; ib < BATCH; ib += 16) {
        float u[16];
#pragma unroll
        for (int q = 0; q < 16; ++q) u[q] = up[(size_t)(ib + q) * NFW];
#pragma unroll
        for (int q = 0; q < 16; ++q) {
            float z = 10.0f * (fw + u[q] - 0.5f);
            fw = 1.0f / (1.0f + __expf(-z));
            fp[(size_t)(ib + q) * NFW] = fw;
        }
    }
}

// ---------------------------------------------------------------------------
// Kernel 4: preds. Block per i: h = relu(fw1 @ xs_i), out[i] = fw2 . h.
// ---------------------------------------------------------------------------
__global__ __launch_bounds__(256) void k_preds(const float* __restrict__ FW,
                                               const float* __restrict__ xs,
                                               float* __restrict__ out) {
    __shared__ float xsh[IN_DIM];
    __shared__ float hsh[HID];
    const int i = blockIdx.x, t = threadIdx.x;
    if (t < 32) {
        f32x4 v = *reinterpret_cast<const f32x4*>(xs + (size_t)i * IN_DIM + t * 4);
        xsh[t*4+0] = v.x; xsh[t*4+1] = v.y; xsh[t*4+2] = v.z; xsh[t*4+3] = v.w;
    }
    __syncthreads();
    const int k = t >> 2, q = t & 3;
    const float* fr = FW + (size_t)i * NFW + k * IN_DIM + q * 32;
    float p = 0.f;
#pragma unroll
    for (int m = 0; m < 8; ++m) {
        f32x4 v = *reinterpret_cast<const f32x4*>(fr + m * 4);
        const int d = q * 32 + m * 4;
        p += v.x * xsh[d] + v.y * xsh[d+1] + v.z * xsh[d+2] + v.w * xsh[d+3];
    }
    p += __shfl_xor(p, 1);
    p += __shfl_xor(p, 2);
    if (q == 0) hsh[k] = fmaxf(p, 0.f);
    __syncthreads();
    if (t < 64) {
        float v = FW[(size_t)i * NFW + IN_DIM * HID + t] * hsh[t];
        v += __shfl_xor(v, 1);  v += __shfl_xor(v, 2);  v += __shfl_xor(v, 4);
        v += __shfl_xor(v, 8);  v += __shfl_xor(v, 16); v += __shfl_xor(v, 32);
        if (t == 0) out[i] = v;
    }
}

// ---------------------------------------------------------------------------
// Workspace layout (~48.6 MiB):
//   W1T  bf16 :  4,227,072 B @ 0
//   Mpart f32 : 25,362,432 B @  4,227,072   (6 x 8256 x 128)
//   Mb   bf16 :  2,113,536 B @ 29,589,504
//   U    f32  :  8,454,144 B @ 31,703,040
//   FW   f32  :  8,454,144 B @ 40,157,184
// ---------------------------------------------------------------------------
extern "C" void kernel_launch(void* const* d_in, const int* in_sizes, int n_in,
                              void* d_out, int out_size, void* d_ws, size_t ws_size,
                              hipStream_t stream) {
    const float* x   = (const float*)d_in[0];   // (256,1,128)
    const float* W1  = (const float*)d_in[1];   // (16512,128)
    const float* W2  = (const float*)d_in[2];   // (8256,16512)
    const float* fw0 = (const float*)d_in[3];   // (8256,)
    float* out = (float*)d_out;                 // 256 f32

    char* ws = (char*)d_ws;
    unsigned short* W1T  = (unsigned short*)(ws);
    float*          Mpart = (float*)(ws + 4227072);
    unsigned short* Mb   = (unsigned short*)(ws + 29589504);
    float*          U    = (float*)(ws + 31703040);
    float*          FW   = (float*)(ws + 40157184);

    hipLaunchKernelGGL(k_prep_w1t, dim3(258),  dim3(256), 0, stream, W1, W1T);
    hipLaunchKernelGGL(k_gemm_M,   dim3(258),  dim3(512), 0, stream, W2, W1T, Mpart);
    hipLaunchKernelGGL(k_reduce_M, dim3(1032), dim3(256), 0, stream, Mpart, Mb);
    hipLaunchKernelGGL(k_gemm_U,   dim3(516),  dim3(256), 0, stream, x, Mb, U);
    hipLaunchKernelGGL(k_chains,   dim3(33),   dim3(256), 0, stream, U, fw0, FW);
    hipLaunchKernelGGL(k_preds,    dim3(256),  dim3(256), 0, stream, FW, x, out);
}